// Round 5
// baseline (7176.572 us; speedup 1.0000x reference)
//
#include <hip/hip_runtime.h>

#define T_STEPS 512
#define BATCH   64
#define HID     1024
#define IN      256
#define KTOT    1280

typedef float  f32x4  __attribute__((ext_vector_type(4)));
typedef short  short8 __attribute__((ext_vector_type(8)));
typedef unsigned short ushort_t;
typedef unsigned int   uint_t;

#define WAITVM(N) asm volatile("s_waitcnt vmcnt(" #N ")" ::: "memory")
#define SB0() __builtin_amdgcn_sched_barrier(0)

// ---------------------------------------------------------------------------
__device__ __forceinline__ ushort_t bf16rn(float f) {
    uint_t u = __builtin_bit_cast(uint_t, f);
    u += 0x7fff + ((u >> 16) & 1);
    return (ushort_t)(u >> 16);
}
__device__ __forceinline__ float bf16f(ushort_t h) {
    return __builtin_bit_cast(float, (uint_t)h << 16);
}
// 8 f32 -> hi/lo bf16 fragments
__device__ __forceinline__ void conv8(float4 a, float4 b, short8& hi, short8& lo) {
    float v[8] = {a.x, a.y, a.z, a.w, b.x, b.y, b.z, b.w};
#pragma unroll
    for (int j = 0; j < 8; ++j) {
        ushort_t h = bf16rn(v[j]);
        ushort_t l = bf16rn(v[j] - bf16f(h));
        hi[j] = (short)h; lo[j] = (short)l;
    }
}

__device__ __forceinline__ f32x4 mfma16(short8 a, short8 b, f32x4 c) {
    return __builtin_amdgcn_mfma_f32_16x16x32_bf16(a, b, c, 0, 0, 0);
}

// L1+L2-bypass 16B load; result valid only after s_waitcnt vmcnt + sched_barrier.
__device__ __forceinline__ short8 load_coh16(const void* p) {
    short8 r;
    asm volatile("global_load_dwordx4 %0, %1, off sc0 sc1" : "=v"(r) : "v"(p));
    return r;
}

struct Frag8 { short8 h[4]; short8 l[4]; };

__device__ __forceinline__ void issue_set(const char* bhi, const char* blo,
                                          int nstride, Frag8& F) {
#pragma unroll
    for (int n = 0; n < 4; ++n) {
        F.h[n] = load_coh16(bhi + n * nstride);
        F.l[n] = load_coh16(blo + n * nstride);
    }
}

__device__ __forceinline__ void mfma_set(short8 ah, short8 al, const Frag8& S, f32x4* acc) {
#pragma unroll
    for (int n = 0; n < 4; ++n) {
        acc[n] = mfma16(ah, S.h[n], acc[n]);
        acc[n] = mfma16(ah, S.l[n], acc[n]);
        acc[n] = mfma16(al, S.h[n], acc[n]);
    }
}

// ---------------------------------------------------------------------------
__global__ __launch_bounds__(256) void init_k(
    float* __restrict__ out, int* __restrict__ flags, const float* __restrict__ bfc)
{
    int i = blockIdx.x * 256 + threadIdx.x;
    if (i < BATCH * T_STEPS) out[i] = bfc[0];
    if (i < 256) flags[i] = 0;
}

// x[b][t][i] -> xhi/xlo [t][b][i] (bf16 hi + residual). grid 512, block 256.
__global__ __launch_bounds__(256) void xprep_k(
    const float* __restrict__ x, ushort_t* __restrict__ xhi, ushort_t* __restrict__ xlo)
{
    const int t = blockIdx.x, i = threadIdx.x;
    for (int b = 0; b < BATCH; ++b) {
        float v = x[((size_t)b * T_STEPS + t) * IN + i];
        ushort_t h = bf16rn(v);
        ushort_t l = bf16rn(v - bf16f(h));
        size_t o = ((size_t)t * BATCH + b) * IN + i;
        xhi[o] = h; xlo[o] = l;
    }
}

// ---------------------------------------------------------------------------
// Persistent fused LSTM, MFMA edition. grid 256, block 512 (8 waves).
// WG owns 4 hidden units = 16 gate rows (M=16). Weights as split-bf16 A-frags
// in REGISTERS (loaded once). Per step: x-part MFMA pre-spin (L2-cached
// loads) -> spin barrier -> 32 coherent B-frag loads (h hi/lo, LIC) ->
// vmcnt(0) -> 48 h MFMAs -> red LDS reduce over 8 waves -> gates -> h hi/lo
// store (sc0 sc1) -> FC atomicAdd -> flag release.
// Frag maps (m89-verified): A/B lane l: row/col=l&15, k=(l>>4)*8+j.
// D: col=lane&15, row=(lane>>4)*4+reg.
// ---------------------------------------------------------------------------
__global__ __launch_bounds__(512) void lstm_seq(
    const float* __restrict__ Whh, const float* __restrict__ Wih,
    const float* __restrict__ bih, const float* __restrict__ bhh,
    const float* __restrict__ Wfc,
    const ushort_t* __restrict__ xhi, const ushort_t* __restrict__ xlo,
    ushort_t* __restrict__ h_hi,  // [2][BATCH][HID] bf16
    ushort_t* __restrict__ h_lo,
    float* __restrict__ out,      // [BATCH][T]
    int* __restrict__ flags)      // [256]
{
    __shared__ float red[8 * 16 * 64];   // 32 KB
    __shared__ float hfc[4 * 64];

    const int tid  = threadIdx.x;
    const int wg   = blockIdx.x;
    const int u0   = wg * 4;
    const int lane = tid & 63;
    const int wv   = tid >> 6;        // wave 0..7
    const int col  = lane & 15;       // M-row (A) / N-col (B,D)
    const int kg   = lane >> 4;       // k-group 0..3

    // ---- one-time: A-fragments (weights, split bf16) into registers ----
    // i=0..3: h k-tiles kt=wv+8i; i=4: x k-tile kt=32+wv.
    short8 aHi[5], aLo[5];
    {
        const size_t grow = (size_t)(col >> 2) * HID + u0 + (col & 3);
#pragma unroll
        for (int i = 0; i < 5; ++i) {
            const int kt = (i < 4) ? (wv + 8 * i) : (32 + wv);
            const int k0 = 32 * kt + kg * 8;
            const float* wp = (i < 4) ? (Whh + grow * HID + k0)
                                      : (Wih + grow * IN + (k0 - 1024));
            float4 wa = *(const float4*)wp;
            float4 wb = *(const float4*)(wp + 4);
            conv8(wa, wb, aHi[i], aLo[i]);
        }
    }

    // lane-invariant byte offsets into v-planes
    const int hoff = col * 2048 + kg * 16;             // h: [b][1024] bf16
    const int xoff = col * 512 + wv * 64 + kg * 16;    // x: [b][256] bf16
    const char* hhiB = (const char*)h_hi;
    const char* hloB = (const char*)h_lo;

    // epilogue constants
    const int ui_ep = (tid >> 6) & 3;
    const int b_ep  = tid & 63;
    float bias_r[4], wfc_r[4];
#pragma unroll
    for (int gi = 0; gi < 4; ++gi)
        bias_r[gi] = bih[gi * HID + u0 + ui_ep] + bhh[gi * HID + u0 + ui_ep];
#pragma unroll
    for (int ui = 0; ui < 4; ++ui) wfc_r[ui] = Wfc[u0 + ui];

    float c_state = 0.f;
    __syncthreads();

    for (int t = 0; t < T_STEPS; ++t) {
        f32x4 acc[4];
#pragma unroll
        for (int n = 0; n < 4; ++n) acc[n] = (f32x4)0.f;

        // ---- x part (independent of h; L2-cached loads; pre-spin) ----
        {
            const char* bh = (const char*)(xhi + (size_t)t * (BATCH * IN)) + xoff;
            const char* bl = (const char*)(xlo + (size_t)t * (BATCH * IN)) + xoff;
            short8 xh[4], xl[4];
#pragma unroll
            for (int n = 0; n < 4; ++n) {
                xh[n] = *(const short8*)(bh + n * 8192);
                xl[n] = *(const short8*)(bl + n * 8192);
            }
#pragma unroll
            for (int n = 0; n < 4; ++n) {
                acc[n] = mfma16(aHi[4], xh[n], acc[n]);
                acc[n] = mfma16(aHi[4], xl[n], acc[n]);
                acc[n] = mfma16(aLo[4], xh[n], acc[n]);
            }
        }

        // ---- h part ----
        if (t > 0) {
            if (wv == 0) {
                for (;;) {
                    int m0 = __hip_atomic_load(flags + lane * 4 + 0, __ATOMIC_RELAXED, __HIP_MEMORY_SCOPE_AGENT);
                    int m1 = __hip_atomic_load(flags + lane * 4 + 1, __ATOMIC_RELAXED, __HIP_MEMORY_SCOPE_AGENT);
                    int m2 = __hip_atomic_load(flags + lane * 4 + 2, __ATOMIC_RELAXED, __HIP_MEMORY_SCOPE_AGENT);
                    int m3 = __hip_atomic_load(flags + lane * 4 + 3, __ATOMIC_RELAXED, __HIP_MEMORY_SCOPE_AGENT);
                    if (__all(min(min(m0, m1), min(m2, m3)) >= t)) break;
                    __builtin_amdgcn_s_sleep(2);
                }
                // no fence: h loads below bypass L1/L2 (sc0 sc1)
            }
            __syncthreads();

            const int buf = ((t - 1) & 1) * 131072;   // bytes per h plane buffer
            const char* bh = hhiB + buf + hoff;
            const char* bl = hloB + buf + hoff;
            Frag8 S0, S1, S2, S3;
            issue_set(bh + (wv +  0) * 64, bl + (wv +  0) * 64, 32768, S0);
            issue_set(bh + (wv +  8) * 64, bl + (wv +  8) * 64, 32768, S1);
            issue_set(bh + (wv + 16) * 64, bl + (wv + 16) * 64, 32768, S2);
            issue_set(bh + (wv + 24) * 64, bl + (wv + 24) * 64, 32768, S3);
            WAITVM(0); SB0();
            mfma_set(aHi[0], aLo[0], S0, acc);
            mfma_set(aHi[1], aLo[1], S1, acc);
            mfma_set(aHi[2], aLo[2], S2, acc);
            mfma_set(aHi[3], aLo[3], S3, acc);
        }

        // ---- park per-wave partials: D row=(kg*4+r), col=(n*16+col) ----
#pragma unroll
        for (int n = 0; n < 4; ++n)
#pragma unroll
            for (int r = 0; r < 4; ++r)
                red[wv * 1024 + (kg * 4 + r) * 64 + n * 16 + col] = acc[n][r];
        __syncthreads();

        // ---- epilogue: gates -> c,h; h hi/lo coherent store; FC partial ----
        if (tid < 256) {
            float pre[4];
#pragma unroll
            for (int gi = 0; gi < 4; ++gi) {
                float s = bias_r[gi];
#pragma unroll
                for (int w8 = 0; w8 < 8; ++w8)
                    s += red[w8 * 1024 + (gi * 4 + ui_ep) * 64 + b_ep];
                pre[gi] = s;
            }
            float ig = 1.f / (1.f + expf(-pre[0]));
            float fg = 1.f / (1.f + expf(-pre[1]));
            float gg = tanhf(pre[2]);
            float og = 1.f / (1.f + expf(-pre[3]));
            c_state = fg * c_state + ig * gg;
            float hv = og * tanhf(c_state);

            ushort_t hh = bf16rn(hv);
            ushort_t hl = bf16rn(hv - bf16f(hh));
            size_t idx = (size_t)(t & 1) * (BATCH * HID) + (size_t)b_ep * HID + u0 + ui_ep;
            asm volatile("global_store_short %0, %1, off sc0 sc1"
                         :: "v"(h_hi + idx), "v"((uint_t)hh) : "memory");
            asm volatile("global_store_short %0, %1, off sc0 sc1"
                         :: "v"(h_lo + idx), "v"((uint_t)hl) : "memory");
            hfc[ui_ep * 64 + b_ep] = hv * wfc_r[ui_ep];
        }
        WAITVM(0);        // every wave drains its own stores before the barrier
        __syncthreads();
        if (tid < 64) {
            float fc = hfc[tid] + hfc[64 + tid] + hfc[128 + tid] + hfc[192 + tid];
            atomicAdd(&out[(size_t)tid * T_STEPS + t], fc);
        }
        if (tid == 0) {
            __hip_atomic_store(flags + wg, t + 1, __ATOMIC_RELAXED, __HIP_MEMORY_SCOPE_AGENT);
        }
    }
}

// ---------------------------------------------------------------------------
extern "C" void kernel_launch(void* const* d_in, const int* in_sizes, int n_in,
                              void* d_out, int out_size, void* d_ws, size_t ws_size,
                              hipStream_t stream)
{
    const float* x   = (const float*)d_in[0];
    const float* Wih = (const float*)d_in[1];
    const float* Whh = (const float*)d_in[2];
    const float* bih = (const float*)d_in[3];
    const float* bhh = (const float*)d_in[4];
    const float* Wfc = (const float*)d_in[5];
    const float* bfc = (const float*)d_in[6];
    float* out = (float*)d_out;

    ushort_t* xhi  = (ushort_t*)d_ws;                         // 512*64*256
    ushort_t* xlo  = xhi + (size_t)T_STEPS * BATCH * IN;      // 512*64*256
    ushort_t* h_hi = xlo + (size_t)T_STEPS * BATCH * IN;      // 2*64*1024
    ushort_t* h_lo = h_hi + 2 * BATCH * HID;                  // 2*64*1024
    int*     flags = (int*)(h_lo + 2 * BATCH * HID);          // 256 ints (~33 MB total)

    init_k<<<dim3((BATCH * T_STEPS + 255) / 256), dim3(256), 0, stream>>>(out, flags, bfc);
    xprep_k<<<dim3(T_STEPS), dim3(256), 0, stream>>>(x, xhi, xlo);
    lstm_seq<<<dim3(256), dim3(512), 0, stream>>>(
        Whh, Wih, bih, bhh, Wfc, xhi, xlo, h_hi, h_lo, out, flags);
}

// Round 7
// 6194.129 us; speedup vs baseline: 1.1586x; 1.1586x over previous
//
#include <hip/hip_runtime.h>

#define T_STEPS 512
#define BATCH   64
#define HID     1024
#define IN      256
#define NWG     128
#define UPW     8             // hidden units per WG (M = 32 gate rows)
#define REDW    2080          // 32*65 floats per wave slice (padded)
// red 8*2080 + hs_hi 256 + hs_lo 256 + wfcs 8   (hs_* are [64][8] ushort = 1024B each)
#define LDS_FLOATS (8*REDW + 256 + 256 + 8)
#define LDS_BYTES  (LDS_FLOATS * 4)

typedef float  f32x4  __attribute__((ext_vector_type(4)));
typedef short  short8 __attribute__((ext_vector_type(8)));
typedef unsigned short ushort_t;
typedef unsigned int   uint_t;

#define WAITVM(N) asm volatile("s_waitcnt vmcnt(" #N ")" ::: "memory")
#define SB0() __builtin_amdgcn_sched_barrier(0)

// ---------------------------------------------------------------------------
__device__ __forceinline__ ushort_t bf16rn(float f) {
    uint_t u = __builtin_bit_cast(uint_t, f);
    u += 0x7fff + ((u >> 16) & 1);
    return (ushort_t)(u >> 16);
}
__device__ __forceinline__ float bf16f(ushort_t h) {
    return __builtin_bit_cast(float, (uint_t)h << 16);
}
__device__ __forceinline__ void conv8(float4 a, float4 b, short8& hi, short8& lo) {
    float v[8] = {a.x, a.y, a.z, a.w, b.x, b.y, b.z, b.w};
#pragma unroll
    for (int j = 0; j < 8; ++j) {
        ushort_t h = bf16rn(v[j]);
        ushort_t l = bf16rn(v[j] - bf16f(h));
        hi[j] = (short)h; lo[j] = (short)l;
    }
}
__device__ __forceinline__ f32x4 mfma16(short8 a, short8 b, f32x4 c) {
    return __builtin_amdgcn_mfma_f32_16x16x32_bf16(a, b, c, 0, 0, 0);
}
// L1/L2-bypass 16B load; data valid only after s_waitcnt vmcnt + sched_barrier.
__device__ __forceinline__ short8 load_coh16(const void* p) {
    short8 r;
    asm volatile("global_load_dwordx4 %0, %1, off sc0 sc1" : "=v"(r) : "v"(p));
    return r;
}

struct Frag8 { short8 h[4]; short8 l[4]; };

__device__ __forceinline__ void issue_set(const char* bhi, const char* blo, Frag8& F) {
#pragma unroll
    for (int n = 0; n < 4; ++n) {
        F.h[n] = load_coh16(bhi + n * 32768);
        F.l[n] = load_coh16(blo + n * 32768);
    }
}

// ---------------------------------------------------------------------------
__global__ __launch_bounds__(256) void init_k(
    float* __restrict__ out, int* __restrict__ flags, const float* __restrict__ bfc)
{
    int i = blockIdx.x * 256 + threadIdx.x;
    if (i < BATCH * T_STEPS) out[i] = bfc[0];
    if (i < 256) flags[i] = 0;
}

// x[b][t][i] -> xhi/xlo [t][b][i] (bf16 hi + residual). grid 512, block 256.
__global__ __launch_bounds__(256) void xprep_k(
    const float* __restrict__ x, ushort_t* __restrict__ xhi, ushort_t* __restrict__ xlo)
{
    const int t = blockIdx.x, i = threadIdx.x;
    for (int b = 0; b < BATCH; ++b) {
        float v = x[((size_t)b * T_STEPS + t) * IN + i];
        ushort_t h = bf16rn(v);
        ushort_t l = bf16rn(v - bf16f(h));
        size_t o = ((size_t)t * BATCH + b) * IN + i;
        xhi[o] = h; xlo[o] = l;
    }
}

// ---------------------------------------------------------------------------
// Persistent fused LSTM, MFMA split-bf16. grid 128, block 512 (8 waves).
// WG owns 8 hidden units = 32 gate rows (2 row-tiles of 16). Waves split K:
// wave wv owns k-tiles {wv, wv+8, wv+16, wv+24} (h) + {32+wv} (x).
// A-frags (weights) persistent in registers. Per step: x MFMAs pre-spin ->
// spin -> 32 coherent B loads (h hi/lo) -> vmcnt(0) -> 96 h MFMAs -> padded
// red LDS reduce -> gates -> h staged in LDS -> 128x 16B coherent stores ->
// flag release -> FC atomicAdd (off critical path).
// ---------------------------------------------------------------------------
__global__ __launch_bounds__(512, 2) void lstm_seq(
    const float* __restrict__ Whh, const float* __restrict__ Wih,
    const float* __restrict__ bih, const float* __restrict__ bhh,
    const float* __restrict__ Wfc,
    const ushort_t* __restrict__ xhi, const ushort_t* __restrict__ xlo,
    ushort_t* __restrict__ h_hi,  // [2][BATCH][HID] bf16
    ushort_t* __restrict__ h_lo,
    float* __restrict__ out,      // [BATCH][T]
    int* __restrict__ flags)      // [NWG]
{
    extern __shared__ float smem[];
    float*    red   = smem;                               // [8][32][65]
    ushort_t* hs_hi = (ushort_t*)(smem + 8 * REDW);       // [64][8] ushort (1024 B)
    ushort_t* hs_lo = (ushort_t*)(smem + 8 * REDW + 256); // [64][8] ushort (1024 B)
    float*    wfcs  = smem + 8 * REDW + 512;              // [8]

    const int tid  = threadIdx.x;
    const int wg   = blockIdx.x;
    const int u0   = wg * UPW;
    const int lane = tid & 63;
    const int wv   = tid >> 6;        // wave 0..7
    const int col  = lane & 15;
    const int kg   = lane >> 4;       // 0..3

    // ---- one-time: A-fragments (weights, split bf16) into registers ----
    short8 aHi[2][5], aLo[2][5];
    {
        const size_t growB = (size_t)(col >> 2) * HID + u0 + (col & 3);
#pragma unroll
        for (int m = 0; m < 2; ++m) {
            const size_t grow = growB + m * 4;
#pragma unroll
            for (int i = 0; i < 5; ++i) {
                const int kt = (i < 4) ? (wv + 8 * i) : (32 + wv);
                const int k0 = 32 * kt + kg * 8;
                const float* wp = (i < 4) ? (Whh + grow * HID + k0)
                                          : (Wih + grow * IN + (k0 - 1024));
                float4 wa = *(const float4*)wp;
                float4 wb = *(const float4*)(wp + 4);
                conv8(wa, wb, aHi[m][i], aLo[m][i]);
            }
        }
    }
    if (tid < UPW) wfcs[tid] = Wfc[u0 + tid];

    const int hoff = col * 2048 + kg * 16;             // h plane [b][1024] bf16
    const int xoff = col * 512 + wv * 64 + kg * 16;    // x plane [b][256]  bf16
    const char* hhiB = (const char*)h_hi;
    const char* hloB = (const char*)h_lo;

    // epilogue constants: thread owns (ui = tid>>6, b = tid&63)
    const int ui_ep = tid >> 6;
    const int b_ep  = tid & 63;
    float bias_r[4];
#pragma unroll
    for (int gi = 0; gi < 4; ++gi)
        bias_r[gi] = bih[gi * HID + u0 + ui_ep] + bhh[gi * HID + u0 + ui_ep];

    float c_state = 0.f;
    __syncthreads();

    for (int t = 0; t < T_STEPS; ++t) {
        f32x4 acc[2][4];
#pragma unroll
        for (int m = 0; m < 2; ++m)
#pragma unroll
            for (int n = 0; n < 4; ++n) acc[m][n] = (f32x4)0.f;

        // ---- x part (independent of h; cached loads; pre-spin overlap) ----
        {
            const char* bh = (const char*)xhi + (size_t)t * 32768 + xoff;
            const char* bl = (const char*)xlo + (size_t)t * 32768 + xoff;
            short8 xh[4], xl[4];
#pragma unroll
            for (int n = 0; n < 4; ++n) {
                xh[n] = *(const short8*)(bh + n * 8192);
                xl[n] = *(const short8*)(bl + n * 8192);
            }
#pragma unroll
            for (int m = 0; m < 2; ++m)
#pragma unroll
                for (int n = 0; n < 4; ++n) {
                    acc[m][n] = mfma16(aHi[m][4], xh[n], acc[m][n]);
                    acc[m][n] = mfma16(aHi[m][4], xl[n], acc[m][n]);
                    acc[m][n] = mfma16(aLo[m][4], xh[n], acc[m][n]);
                }
        }

        // ---- h part ----
        if (t > 0) {
            if (wv == 0) {
                for (;;) {
                    int m0 = __hip_atomic_load(flags + lane, __ATOMIC_RELAXED, __HIP_MEMORY_SCOPE_AGENT);
                    int m1 = __hip_atomic_load(flags + 64 + lane, __ATOMIC_RELAXED, __HIP_MEMORY_SCOPE_AGENT);
                    if (__all(min(m0, m1) >= t)) break;
                    __builtin_amdgcn_s_sleep(2);
                }
            }
            __syncthreads();

            const int buf = ((t - 1) & 1) * 131072;
            const char* bh = hhiB + buf + hoff;
            const char* bl = hloB + buf + hoff;
            Frag8 S0, S1, S2, S3;
            issue_set(bh + (wv +  0) * 64, bl + (wv +  0) * 64, S0);
            issue_set(bh + (wv +  8) * 64, bl + (wv +  8) * 64, S1);
            issue_set(bh + (wv + 16) * 64, bl + (wv + 16) * 64, S2);
            issue_set(bh + (wv + 24) * 64, bl + (wv + 24) * 64, S3);
            WAITVM(0); SB0();
#pragma unroll
            for (int m = 0; m < 2; ++m)
#pragma unroll
                for (int n = 0; n < 4; ++n) {
                    acc[m][n] = mfma16(aHi[m][0], S0.h[n], acc[m][n]);
                    acc[m][n] = mfma16(aHi[m][0], S0.l[n], acc[m][n]);
                    acc[m][n] = mfma16(aLo[m][0], S0.h[n], acc[m][n]);
                    acc[m][n] = mfma16(aHi[m][1], S1.h[n], acc[m][n]);
                    acc[m][n] = mfma16(aHi[m][1], S1.l[n], acc[m][n]);
                    acc[m][n] = mfma16(aLo[m][1], S1.h[n], acc[m][n]);
                    acc[m][n] = mfma16(aHi[m][2], S2.h[n], acc[m][n]);
                    acc[m][n] = mfma16(aHi[m][2], S2.l[n], acc[m][n]);
                    acc[m][n] = mfma16(aLo[m][2], S2.h[n], acc[m][n]);
                    acc[m][n] = mfma16(aHi[m][3], S3.h[n], acc[m][n]);
                    acc[m][n] = mfma16(aHi[m][3], S3.l[n], acc[m][n]);
                    acc[m][n] = mfma16(aLo[m][3], S3.h[n], acc[m][n]);
                }
        }

        // ---- park per-wave partials (padded rows: conflict-free) ----
        // D: row_loc = m*16 + kg*4 + r, col_b = n*16 + col
#pragma unroll
        for (int m = 0; m < 2; ++m)
#pragma unroll
            for (int n = 0; n < 4; ++n)
#pragma unroll
                for (int r = 0; r < 4; ++r)
                    red[wv * REDW + (m * 16 + kg * 4 + r) * 65 + n * 16 + col] = acc[m][n][r];
        __syncthreads();

        // ---- epilogue: all 512 threads, one (ui,b) each ----
        {
            float pre[4];
#pragma unroll
            for (int gi = 0; gi < 4; ++gi) {
                const int row_loc = (ui_ep >> 2) * 16 + gi * 4 + (ui_ep & 3);
                float s = bias_r[gi];
#pragma unroll
                for (int w8 = 0; w8 < 8; ++w8)
                    s += red[w8 * REDW + row_loc * 65 + b_ep];
                pre[gi] = s;
            }
            float ig = 1.f / (1.f + expf(-pre[0]));
            float fg = 1.f / (1.f + expf(-pre[1]));
            float gg = tanhf(pre[2]);
            float og = 1.f / (1.f + expf(-pre[3]));
            c_state = fg * c_state + ig * gg;
            float hv = og * tanhf(c_state);
            ushort_t hh = bf16rn(hv);
            ushort_t hl = bf16rn(hv - bf16f(hh));
            hs_hi[b_ep * UPW + ui_ep] = hh;
            hs_lo[b_ep * UPW + ui_ep] = hl;
        }
        __syncthreads();

        // ---- coalesced coherent h stores: 128 threads x one dwordx4 ----
        if (tid < 128) {
            const int b = tid & 63, p = tid >> 6;
            const ushort_t* src = (p ? hs_lo : hs_hi) + b * UPW;
            short8 v = *(const short8*)src;
            ushort_t* dst = (p ? h_lo : h_hi) + (size_t)(t & 1) * (BATCH * HID)
                            + (size_t)b * HID + u0;
            asm volatile("global_store_dwordx4 %0, %1, off sc0 sc1"
                         :: "v"(dst), "v"(v) : "memory");
        }
        WAITVM(0);        // drain h stores wave-wide before the barrier
        __syncthreads();
        if (tid == 0)
            __hip_atomic_store(flags + wg, t + 1, __ATOMIC_RELAXED, __HIP_MEMORY_SCOPE_AGENT);

        // ---- FC partial (after release; off critical path) ----
        if (tid < 64) {
            float s = 0.f;
#pragma unroll
            for (int ui = 0; ui < UPW; ++ui)
                s += (bf16f(hs_hi[tid * UPW + ui]) + bf16f(hs_lo[tid * UPW + ui])) * wfcs[ui];
            atomicAdd(&out[(size_t)tid * T_STEPS + t], s);
        }
    }
}

// ---------------------------------------------------------------------------
extern "C" void kernel_launch(void* const* d_in, const int* in_sizes, int n_in,
                              void* d_out, int out_size, void* d_ws, size_t ws_size,
                              hipStream_t stream)
{
    const float* x   = (const float*)d_in[0];
    const float* Wih = (const float*)d_in[1];
    const float* Whh = (const float*)d_in[2];
    const float* bih = (const float*)d_in[3];
    const float* bhh = (const float*)d_in[4];
    const float* Wfc = (const float*)d_in[5];
    const float* bfc = (const float*)d_in[6];
    float* out = (float*)d_out;

    ushort_t* xhi  = (ushort_t*)d_ws;                         // 512*64*256
    ushort_t* xlo  = xhi + (size_t)T_STEPS * BATCH * IN;      // 512*64*256
    ushort_t* h_hi = xlo + (size_t)T_STEPS * BATCH * IN;      // 2*64*1024
    ushort_t* h_lo = h_hi + 2 * BATCH * HID;                  // 2*64*1024
    int*     flags = (int*)(h_lo + 2 * BATCH * HID);          // 256 ints

    (void)hipFuncSetAttribute((const void*)lstm_seq,
                              hipFuncAttributeMaxDynamicSharedMemorySize, LDS_BYTES);

    init_k<<<dim3((BATCH * T_STEPS + 255) / 256), dim3(256), 0, stream>>>(out, flags, bfc);
    xprep_k<<<dim3(T_STEPS), dim3(256), 0, stream>>>(x, xhi, xlo);
    lstm_seq<<<dim3(NWG), dim3(512), LDS_BYTES, stream>>>(
        Whh, Wih, bih, bhh, Wfc, xhi, xlo, h_hi, h_lo, out, flags);
}

// Round 14
// 4077.142 us; speedup vs baseline: 1.7602x; 1.5192x over previous
//
#include <hip/hip_runtime.h>

#define T_STEPS 512
#define BATCH   64
#define HID     1024
#define IN      256
#define NWG     128
#define UPW     8             // hidden units per WG (M = 32 gate rows)
#define REDW    2080          // 32*65 floats per wave slice (padded)
#define LDS_FLOATS (8*REDW + 256 + 8)   // red + hs_hi(1024B) + wfcs
#define LDS_BYTES  (LDS_FLOATS * 4)

typedef float  f32x4  __attribute__((ext_vector_type(4)));
typedef short  short8 __attribute__((ext_vector_type(8)));
typedef unsigned short ushort_t;
typedef unsigned int   uint_t;

#define WAITVM(N) asm volatile("s_waitcnt vmcnt(" #N ")" ::: "memory")
#define SB0() __builtin_amdgcn_sched_barrier(0)

// ---------------------------------------------------------------------------
__device__ __forceinline__ ushort_t bf16rn(float f) {
    uint_t u = __builtin_bit_cast(uint_t, f);
    u += 0x7fff + ((u >> 16) & 1);
    return (ushort_t)(u >> 16);
}
__device__ __forceinline__ float bf16f(ushort_t h) {
    return __builtin_bit_cast(float, (uint_t)h << 16);
}
__device__ __forceinline__ void conv8(float4 a, float4 b, short8& hi, short8& lo) {
    float v[8] = {a.x, a.y, a.z, a.w, b.x, b.y, b.z, b.w};
#pragma unroll
    for (int j = 0; j < 8; ++j) {
        ushort_t h = bf16rn(v[j]);
        ushort_t l = bf16rn(v[j] - bf16f(h));
        hi[j] = (short)h; lo[j] = (short)l;
    }
}
__device__ __forceinline__ f32x4 mfma16(short8 a, short8 b, f32x4 c) {
    return __builtin_amdgcn_mfma_f32_16x16x32_bf16(a, b, c, 0, 0, 0);
}
// L1/L2-bypass 16B load; data valid only after s_waitcnt vmcnt(0) + sched_barrier.
__device__ __forceinline__ short8 load_coh16(const void* p) {
    short8 r;
    asm volatile("global_load_dwordx4 %0, %1, off sc0 sc1" : "=v"(r) : "v"(p));
    return r;
}

struct Frag4 { short8 h[4]; };

__device__ __forceinline__ void issue_set(const char* bhi, Frag4& F) {
#pragma unroll
    for (int n = 0; n < 4; ++n)
        F.h[n] = load_coh16(bhi + n * 32768);
}

// ---------------------------------------------------------------------------
// out init (b_fc) + flag clear.  grid 128 x 256.
__global__ __launch_bounds__(256) void init_k(
    float* __restrict__ out, int* __restrict__ flags, const float* __restrict__ bfc)
{
    int i = blockIdx.x * 256 + threadIdx.x;
    if (i < BATCH * T_STEPS) out[i] = bfc[0];
    if (i < 256) flags[i] = 0;
}

// x[b][t][i] -> xhi/xlo [t][b][i] (bf16 hi + residual). grid 512, block 256.
__global__ __launch_bounds__(256) void xprep_k(
    const float* __restrict__ x, ushort_t* __restrict__ xhi, ushort_t* __restrict__ xlo)
{
    const int t = blockIdx.x, i = threadIdx.x;
    for (int b = 0; b < BATCH; ++b) {
        float v = x[((size_t)b * T_STEPS + t) * IN + i];
        ushort_t h = bf16rn(v);
        ushort_t l = bf16rn(v - bf16f(h));
        size_t o = ((size_t)t * BATCH + b) * IN + i;
        xhi[o] = h; xlo[o] = l;
    }
}

// ---------------------------------------------------------------------------
// Persistent fused LSTM, MFMA split-bf16 weights/x, SINGLE-plane bf16 h.
// grid 128, block 512 (8 waves). EXACT R7 skeleton (uniform tail — the only
// tail structure that has ever passed; divergent tails NaN'd 4x):
// x MFMAs pre-spin -> wave0 spins on ALL 128 flags -> __syncthreads ->
// all waves issue ALL 16 coherent h loads -> single vmcnt(0)+sched_barrier
// -> 64 h MFMAs -> red reduce (bar) -> epilogue gates -> hs staging (bar)
// -> tid<64 h store -> ALL waves WAITVM(0) -> bar -> tid0 release ->
// tid<64 FC atomicAdd.
// ---------------------------------------------------------------------------
__global__ __launch_bounds__(512, 2) void lstm_seq(
    const float* __restrict__ Whh, const float* __restrict__ Wih,
    const float* __restrict__ bih, const float* __restrict__ bhh,
    const float* __restrict__ Wfc,
    const ushort_t* __restrict__ xhi, const ushort_t* __restrict__ xlo,
    ushort_t* __restrict__ h_hi,  // [2][BATCH][HID] bf16
    float* __restrict__ out,      // [BATCH][T]
    int* __restrict__ flags)      // [NWG]
{
    extern __shared__ float smem[];
    float*    red   = smem;                               // [8][32][65]
    ushort_t* hs_hi = (ushort_t*)(smem + 8 * REDW);       // [64][8] ushort (1024 B)
    float*    wfcs  = smem + 8 * REDW + 256;              // [8]

    const int tid  = threadIdx.x;
    const int wg   = blockIdx.x;
    const int u0   = wg * UPW;
    const int lane = tid & 63;
    const int wv   = tid >> 6;        // wave 0..7
    const int col  = lane & 15;
    const int kg   = lane >> 4;       // 0..3

    // ---- one-time: A-fragments (weights, split bf16) into registers ----
    // h k-tiles: kt = wv + 8*i (i<4); x k-tile: 32+wv.  (R7 mapping)
    short8 aHi[2][5], aLo[2][5];
    {
        const size_t growB = (size_t)(col >> 2) * HID + u0 + (col & 3);
#pragma unroll
        for (int m = 0; m < 2; ++m) {
            const size_t grow = growB + m * 4;
#pragma unroll
            for (int i = 0; i < 5; ++i) {
                const int kt = (i < 4) ? (wv + 8 * i) : (32 + wv);
                const int k0 = 32 * kt + kg * 8;
                const float* wp = (i < 4) ? (Whh + grow * HID + k0)
                                          : (Wih + grow * IN + (k0 - 1024));
                float4 wa = *(const float4*)wp;
                float4 wb = *(const float4*)(wp + 4);
                conv8(wa, wb, aHi[m][i], aLo[m][i]);
            }
        }
    }
    if (tid < UPW) wfcs[tid] = Wfc[u0 + tid];

    const int hoff = col * 2048 + kg * 16;             // h plane [b][1024] bf16
    const int xoff = col * 512 + wv * 64 + kg * 16;    // x plane [b][256]  bf16
    const char* hhiB = (const char*)h_hi;

    // epilogue constants: thread owns (ui = tid>>6, b = tid&63)
    const int ui_ep = tid >> 6;
    const int b_ep  = tid & 63;
    float bias_r[4];
#pragma unroll
    for (int gi = 0; gi < 4; ++gi)
        bias_r[gi] = bih[gi * HID + u0 + ui_ep] + bhh[gi * HID + u0 + ui_ep];

    float c_state = 0.f;
    __syncthreads();

    for (int t = 0; t < T_STEPS; ++t) {
        f32x4 acc[2][4];
#pragma unroll
        for (int m = 0; m < 2; ++m)
#pragma unroll
            for (int n = 0; n < 4; ++n) acc[m][n] = (f32x4)0.f;

        // ---- x part (independent of h; cached loads; pre-spin overlap) ----
        {
            const char* bh = (const char*)xhi + (size_t)t * 32768 + xoff;
            const char* bl = (const char*)xlo + (size_t)t * 32768 + xoff;
            short8 xh[4], xl[4];
#pragma unroll
            for (int n = 0; n < 4; ++n) {
                xh[n] = *(const short8*)(bh + n * 8192);
                xl[n] = *(const short8*)(bl + n * 8192);
            }
#pragma unroll
            for (int m = 0; m < 2; ++m)
#pragma unroll
                for (int n = 0; n < 4; ++n) {
                    acc[m][n] = mfma16(aHi[m][4], xh[n], acc[m][n]);
                    acc[m][n] = mfma16(aHi[m][4], xl[n], acc[m][n]);
                    acc[m][n] = mfma16(aLo[m][4], xh[n], acc[m][n]);
                }
        }

        // ---- h part: wave0 spins on ALL flags, then all waves load ----
        if (t > 0) {
            if (wv == 0) {
                for (;;) {
                    int m0 = __hip_atomic_load(flags + lane, __ATOMIC_RELAXED, __HIP_MEMORY_SCOPE_AGENT);
                    int m1 = __hip_atomic_load(flags + 64 + lane, __ATOMIC_RELAXED, __HIP_MEMORY_SCOPE_AGENT);
                    if (__all(min(m0, m1) >= t)) break;
                    __builtin_amdgcn_s_sleep(1);
                }
            }
            __syncthreads();

            const int buf = ((t - 1) & 1) * 131072;   // bytes per h buffer
            const char* bh = hhiB + buf + hoff;
            Frag4 S0, S1, S2, S3;
            issue_set(bh + (wv +  0) * 64, S0);
            issue_set(bh + (wv +  8) * 64, S1);
            issue_set(bh + (wv + 16) * 64, S2);
            issue_set(bh + (wv + 24) * 64, S3);
            WAITVM(0); SB0();
#pragma unroll
            for (int m = 0; m < 2; ++m)
#pragma unroll
                for (int n = 0; n < 4; ++n) {
                    acc[m][n] = mfma16(aHi[m][0], S0.h[n], acc[m][n]);
                    acc[m][n] = mfma16(aLo[m][0], S0.h[n], acc[m][n]);
                    acc[m][n] = mfma16(aHi[m][1], S1.h[n], acc[m][n]);
                    acc[m][n] = mfma16(aLo[m][1], S1.h[n], acc[m][n]);
                    acc[m][n] = mfma16(aHi[m][2], S2.h[n], acc[m][n]);
                    acc[m][n] = mfma16(aLo[m][2], S2.h[n], acc[m][n]);
                    acc[m][n] = mfma16(aHi[m][3], S3.h[n], acc[m][n]);
                    acc[m][n] = mfma16(aLo[m][3], S3.h[n], acc[m][n]);
                }
        }

        // ---- park per-wave partials (padded rows: conflict-free) ----
#pragma unroll
        for (int m = 0; m < 2; ++m)
#pragma unroll
            for (int n = 0; n < 4; ++n)
#pragma unroll
                for (int r = 0; r < 4; ++r)
                    red[wv * REDW + (m * 16 + kg * 4 + r) * 65 + n * 16 + col] = acc[m][n][r];
        __syncthreads();

        // ---- epilogue: all 512 threads, one (ui,b) each ----
        {
            float pre[4];
#pragma unroll
            for (int gi = 0; gi < 4; ++gi) {
                const int row_loc = (ui_ep >> 2) * 16 + gi * 4 + (ui_ep & 3);
                float s = bias_r[gi];
#pragma unroll
                for (int w8 = 0; w8 < 8; ++w8)
                    s += red[w8 * REDW + row_loc * 65 + b_ep];
                pre[gi] = s;
            }
            float ig = 1.f / (1.f + expf(-pre[0]));
            float fg = 1.f / (1.f + expf(-pre[1]));
            float gg = tanhf(pre[2]);
            float og = 1.f / (1.f + expf(-pre[3]));
            c_state = fg * c_state + ig * gg;
            float hv = og * tanhf(c_state);
            hs_hi[b_ep * UPW + ui_ep] = bf16rn(hv);
        }
        __syncthreads();

        // ---- uniform tail (R7-proven): coalesced h store by tid<64 ----
        if (tid < 64) {
            short8 v = *(const short8*)(hs_hi + (size_t)tid * UPW);
            ushort_t* dst = h_hi + (size_t)(t & 1) * (BATCH * HID)
                            + (size_t)tid * HID + u0;
            asm volatile("global_store_dwordx4 %0, %1, off sc0 sc1"
                         :: "v"(dst), "v"(v) : "memory");
        }
        WAITVM(0);        // drain h stores wave-wide before the barrier
        __syncthreads();
        if (tid == 0)     // release first (ahead of FC issue in wave0)
            __hip_atomic_store(flags + wg, t + 1, __ATOMIC_RELAXED, __HIP_MEMORY_SCOPE_AGENT);
        // ---- FC partial (after release; off critical path) ----
        if (tid < 64) {
            float s = 0.f;
#pragma unroll
            for (int ui = 0; ui < UPW; ++ui)
                s += bf16f(hs_hi[tid * UPW + ui]) * wfcs[ui];
            atomicAdd(&out[(size_t)tid * T_STEPS + t], s);
        }
    }
}

// ---------------------------------------------------------------------------
extern "C" void kernel_launch(void* const* d_in, const int* in_sizes, int n_in,
                              void* d_out, int out_size, void* d_ws, size_t ws_size,
                              hipStream_t stream)
{
    const float* x   = (const float*)d_in[0];
    const float* Wih = (const float*)d_in[1];
    const float* Whh = (const float*)d_in[2];
    const float* bih = (const float*)d_in[3];
    const float* bhh = (const float*)d_in[4];
    const float* Wfc = (const float*)d_in[5];
    const float* bfc = (const float*)d_in[6];
    float* out = (float*)d_out;

    ushort_t* xhi  = (ushort_t*)d_ws;                         // 512*64*256
    ushort_t* xlo  = xhi + (size_t)T_STEPS * BATCH * IN;      // 512*64*256
    ushort_t* h_hi = xlo + (size_t)T_STEPS * BATCH * IN;      // 2*64*1024
    int*     flags = (int*)(h_hi + 2 * BATCH * HID);          // 256 ints

    (void)hipFuncSetAttribute((const void*)lstm_seq,
                              hipFuncAttributeMaxDynamicSharedMemorySize, LDS_BYTES);

    init_k<<<dim3((BATCH * T_STEPS + 255) / 256), dim3(256), 0, stream>>>(out, flags, bfc);
    xprep_k<<<dim3(T_STEPS), dim3(256), 0, stream>>>(x, xhi, xlo);
    lstm_seq<<<dim3(NWG), dim3(512), LDS_BYTES, stream>>>(
        Whh, Wih, bih, bhh, Wfc, xhi, xlo, h_hi, out, flags);
}

// Round 15
// 3955.920 us; speedup vs baseline: 1.8141x; 1.0306x over previous
//
#include <hip/hip_runtime.h>

#define T_STEPS 512
#define BATCH   64
#define HID     1024
#define IN      256
#define NWG     128
#define UPW     8             // hidden units per WG (M = 32 gate rows)
#define REDW    2080          // 32*65 floats per wave slice (padded)
#define LDS_FLOATS (8*REDW + 256 + 8)   // red + hs_hi(1024B) + wfcs
#define LDS_BYTES  (LDS_FLOATS * 4)

typedef float  f32x4  __attribute__((ext_vector_type(4)));
typedef short  short8 __attribute__((ext_vector_type(8)));
typedef unsigned short ushort_t;
typedef unsigned int   uint_t;

#define WAITVM(N) asm volatile("s_waitcnt vmcnt(" #N ")" ::: "memory")
#define SB0() __builtin_amdgcn_sched_barrier(0)

// ---------------------------------------------------------------------------
__device__ __forceinline__ ushort_t bf16rn(float f) {
    uint_t u = __builtin_bit_cast(uint_t, f);
    u += 0x7fff + ((u >> 16) & 1);
    return (ushort_t)(u >> 16);
}
__device__ __forceinline__ float bf16f(ushort_t h) {
    return __builtin_bit_cast(float, (uint_t)h << 16);
}
__device__ __forceinline__ void conv8(float4 a, float4 b, short8& hi, short8& lo) {
    float v[8] = {a.x, a.y, a.z, a.w, b.x, b.y, b.z, b.w};
#pragma unroll
    for (int j = 0; j < 8; ++j) {
        ushort_t h = bf16rn(v[j]);
        ushort_t l = bf16rn(v[j] - bf16f(h));
        hi[j] = (short)h; lo[j] = (short)l;
    }
}
__device__ __forceinline__ f32x4 mfma16(short8 a, short8 b, f32x4 c) {
    return __builtin_amdgcn_mfma_f32_16x16x32_bf16(a, b, c, 0, 0, 0);
}
// L1/L2-bypass 16B load; data valid only after s_waitcnt vmcnt(0) + sched_barrier.
__device__ __forceinline__ short8 load_coh16(const void* p) {
    short8 r;
    asm volatile("global_load_dwordx4 %0, %1, off sc0 sc1" : "=v"(r) : "v"(p));
    return r;
}

struct Frag4 { short8 h[4]; };

__device__ __forceinline__ void issue_set(const char* bhi, Frag4& F) {
#pragma unroll
    for (int n = 0; n < 4; ++n)
        F.h[n] = load_coh16(bhi + n * 32768);
}

// ---------------------------------------------------------------------------
// out init (b_fc) + flag clear.  grid 128 x 256.
__global__ __launch_bounds__(256) void init_k(
    float* __restrict__ out, int* __restrict__ flags, const float* __restrict__ bfc)
{
    int i = blockIdx.x * 256 + threadIdx.x;
    if (i < BATCH * T_STEPS) out[i] = bfc[0];
    if (i < 256) flags[i] = 0;
}

// x[b][t][i] -> xhi/xlo [t][b][i] (bf16 hi + residual). grid 512, block 256.
__global__ __launch_bounds__(256) void xprep_k(
    const float* __restrict__ x, ushort_t* __restrict__ xhi, ushort_t* __restrict__ xlo)
{
    const int t = blockIdx.x, i = threadIdx.x;
    for (int b = 0; b < BATCH; ++b) {
        float v = x[((size_t)b * T_STEPS + t) * IN + i];
        ushort_t h = bf16rn(v);
        ushort_t l = bf16rn(v - bf16f(h));
        size_t o = ((size_t)t * BATCH + b) * IN + i;
        xhi[o] = h; xlo[o] = l;
    }
}

// ---------------------------------------------------------------------------
// Persistent fused LSTM, MFMA split-bf16 weights/x, single-plane bf16 h.
// grid 128, block 512 (8 waves). R14 skeleton + ONE delta: PER-WAVE producer
// spin. Wave wv owns contiguous h k-tiles {4wv..4wv+3} (producers: WGs
// 16wv..16wv+15) + x k-tile wv; it spins only on its own 16 producer flags
// and starts its coherent loads immediately (straggler overlap). Lap-safe:
// union of the 8 waves' producer sets = all 128 WGs, and the WG barrier
// before the h-store means h[t+1] can't overwrite h[t-1] early. Uniform
// tail (the only structure that ever passed; divergent tails NaN'd 4x):
// tid<64 h store -> ALL waves WAITVM(0) -> bar -> tid0 release -> tid<64 FC.
// ---------------------------------------------------------------------------
__global__ __launch_bounds__(512, 2) void lstm_seq(
    const float* __restrict__ Whh, const float* __restrict__ Wih,
    const float* __restrict__ bih, const float* __restrict__ bhh,
    const float* __restrict__ Wfc,
    const ushort_t* __restrict__ xhi, const ushort_t* __restrict__ xlo,
    ushort_t* __restrict__ h_hi,  // [2][BATCH][HID] bf16
    float* __restrict__ out,      // [BATCH][T]
    int* __restrict__ flags)      // [NWG]
{
    extern __shared__ float smem[];
    float*    red   = smem;                               // [8][32][65]
    ushort_t* hs_hi = (ushort_t*)(smem + 8 * REDW);       // [64][8] ushort (1024 B)
    float*    wfcs  = smem + 8 * REDW + 256;              // [8]

    const int tid  = threadIdx.x;
    const int wg   = blockIdx.x;
    const int u0   = wg * UPW;
    const int lane = tid & 63;
    const int wv   = tid >> 6;        // wave 0..7
    const int col  = lane & 15;
    const int kg   = lane >> 4;       // 0..3

    // ---- one-time: A-fragments (weights, split bf16) into registers ----
    // h k-tiles: kt = 4*wv + i (i<4)  [contiguous per wave]; x k-tile: wv.
    short8 aHi[2][5], aLo[2][5];
    {
        const size_t growB = (size_t)(col >> 2) * HID + u0 + (col & 3);
#pragma unroll
        for (int m = 0; m < 2; ++m) {
            const size_t grow = growB + m * 4;
#pragma unroll
            for (int i = 0; i < 5; ++i) {
                const int k0 = (i < 4) ? (128 * wv + 32 * i + kg * 8)
                                       : (32 * wv + kg * 8);
                const float* wp = (i < 4) ? (Whh + grow * HID + k0)
                                          : (Wih + grow * IN + k0);
                float4 wa = *(const float4*)wp;
                float4 wb = *(const float4*)(wp + 4);
                conv8(wa, wb, aHi[m][i], aLo[m][i]);
            }
        }
    }
    if (tid < UPW) wfcs[tid] = Wfc[u0 + tid];

    const int hoff = col * 2048 + kg * 16;             // h plane [b][1024] bf16
    const int xoff = col * 512 + wv * 64 + kg * 16;    // x plane [b][256]  bf16
    const char* hhiB = (const char*)h_hi;
    const int pf = wv * 16 + col;                      // this wave's producer flag

    // epilogue constants: thread owns (ui = tid>>6, b = tid&63)
    const int ui_ep = tid >> 6;
    const int b_ep  = tid & 63;
    float bias_r[4];
#pragma unroll
    for (int gi = 0; gi < 4; ++gi)
        bias_r[gi] = bih[gi * HID + u0 + ui_ep] + bhh[gi * HID + u0 + ui_ep];

    float c_state = 0.f;
    __syncthreads();

    for (int t = 0; t < T_STEPS; ++t) {
        f32x4 acc[2][4];
#pragma unroll
        for (int m = 0; m < 2; ++m)
#pragma unroll
            for (int n = 0; n < 4; ++n) acc[m][n] = (f32x4)0.f;

        // ---- x part (independent of h; cached loads; pre-spin overlap) ----
        {
            const char* bh = (const char*)xhi + (size_t)t * 32768 + xoff;
            const char* bl = (const char*)xlo + (size_t)t * 32768 + xoff;
            short8 xh[4], xl[4];
#pragma unroll
            for (int n = 0; n < 4; ++n) {
                xh[n] = *(const short8*)(bh + n * 8192);
                xl[n] = *(const short8*)(bl + n * 8192);
            }
#pragma unroll
            for (int m = 0; m < 2; ++m)
#pragma unroll
                for (int n = 0; n < 4; ++n) {
                    acc[m][n] = mfma16(aHi[m][4], xh[n], acc[m][n]);
                    acc[m][n] = mfma16(aHi[m][4], xl[n], acc[m][n]);
                    acc[m][n] = mfma16(aLo[m][4], xh[n], acc[m][n]);
                }
        }

        // ---- h part: PER-WAVE spin on own 16 producers, then loads ----
        if (t > 0) {
            for (;;) {
                int f = __hip_atomic_load(flags + pf, __ATOMIC_RELAXED, __HIP_MEMORY_SCOPE_AGENT);
                if (__all(f >= t)) break;
                __builtin_amdgcn_s_sleep(1);
            }
            SB0();

            const int buf = ((t - 1) & 1) * 131072;   // bytes per h buffer
            const char* bh = hhiB + buf + hoff + wv * 256;   // tile 4wv
            Frag4 S0, S1, S2, S3;
            issue_set(bh +   0, S0);
            issue_set(bh +  64, S1);
            issue_set(bh + 128, S2);
            issue_set(bh + 192, S3);
            WAITVM(0); SB0();     // all 16 landed; only now touch the frags
#pragma unroll
            for (int m = 0; m < 2; ++m)
#pragma unroll
                for (int n = 0; n < 4; ++n) {
                    acc[m][n] = mfma16(aHi[m][0], S0.h[n], acc[m][n]);
                    acc[m][n] = mfma16(aLo[m][0], S0.h[n], acc[m][n]);
                    acc[m][n] = mfma16(aHi[m][1], S1.h[n], acc[m][n]);
                    acc[m][n] = mfma16(aLo[m][1], S1.h[n], acc[m][n]);
                    acc[m][n] = mfma16(aHi[m][2], S2.h[n], acc[m][n]);
                    acc[m][n] = mfma16(aLo[m][2], S2.h[n], acc[m][n]);
                    acc[m][n] = mfma16(aHi[m][3], S3.h[n], acc[m][n]);
                    acc[m][n] = mfma16(aLo[m][3], S3.h[n], acc[m][n]);
                }
        }

        // ---- park per-wave partials (padded rows: conflict-free) ----
#pragma unroll
        for (int m = 0; m < 2; ++m)
#pragma unroll
            for (int n = 0; n < 4; ++n)
#pragma unroll
                for (int r = 0; r < 4; ++r)
                    red[wv * REDW + (m * 16 + kg * 4 + r) * 65 + n * 16 + col] = acc[m][n][r];
        __syncthreads();

        // ---- epilogue: all 512 threads, one (ui,b) each ----
        {
            float pre[4];
#pragma unroll
            for (int gi = 0; gi < 4; ++gi) {
                const int row_loc = (ui_ep >> 2) * 16 + gi * 4 + (ui_ep & 3);
                float s = bias_r[gi];
#pragma unroll
                for (int w8 = 0; w8 < 8; ++w8)
                    s += red[w8 * REDW + row_loc * 65 + b_ep];
                pre[gi] = s;
            }
            float ig = 1.f / (1.f + expf(-pre[0]));
            float fg = 1.f / (1.f + expf(-pre[1]));
            float gg = tanhf(pre[2]);
            float og = 1.f / (1.f + expf(-pre[3]));
            c_state = fg * c_state + ig * gg;
            float hv = og * tanhf(c_state);
            hs_hi[b_ep * UPW + ui_ep] = bf16rn(hv);
        }
        __syncthreads();

        // ---- uniform tail (R7/R14-proven): coalesced h store by tid<64 ----
        if (tid < 64) {
            short8 v = *(const short8*)(hs_hi + (size_t)tid * UPW);
            ushort_t* dst = h_hi + (size_t)(t & 1) * (BATCH * HID)
                            + (size_t)tid * HID + u0;
            asm volatile("global_store_dwordx4 %0, %1, off sc0 sc1"
                         :: "v"(dst), "v"(v) : "memory");
        }
        WAITVM(0);        // drain h stores wave-wide before the barrier
        __syncthreads();
        if (tid == 0)     // release first (ahead of FC issue in wave0)
            __hip_atomic_store(flags + wg, t + 1, __ATOMIC_RELAXED, __HIP_MEMORY_SCOPE_AGENT);
        // ---- FC partial (after release; off critical path) ----
        if (tid < 64) {
            float s = 0.f;
#pragma unroll
            for (int ui = 0; ui < UPW; ++ui)
                s += bf16f(hs_hi[tid * UPW + ui]) * wfcs[ui];
            atomicAdd(&out[(size_t)tid * T_STEPS + t], s);
        }
    }
}

// ---------------------------------------------------------------------------
extern "C" void kernel_launch(void* const* d_in, const int* in_sizes, int n_in,
                              void* d_out, int out_size, void* d_ws, size_t ws_size,
                              hipStream_t stream)
{
    const float* x   = (const float*)d_in[0];
    const float* Wih = (const float*)d_in[1];
    const float* Whh = (const float*)d_in[2];
    const float* bih = (const float*)d_in[3];
    const float* bhh = (const float*)d_in[4];
    const float* Wfc = (const float*)d_in[5];
    const float* bfc = (const float*)d_in[6];
    float* out = (float*)d_out;

    ushort_t* xhi  = (ushort_t*)d_ws;                         // 512*64*256
    ushort_t* xlo  = xhi + (size_t)T_STEPS * BATCH * IN;      // 512*64*256
    ushort_t* h_hi = xlo + (size_t)T_STEPS * BATCH * IN;      // 2*64*1024
    int*     flags = (int*)(h_hi + 2 * BATCH * HID);          // 256 ints

    (void)hipFuncSetAttribute((const void*)lstm_seq,
                              hipFuncAttributeMaxDynamicSharedMemorySize, LDS_BYTES);

    init_k<<<dim3((BATCH * T_STEPS + 255) / 256), dim3(256), 0, stream>>>(out, flags, bfc);
    xprep_k<<<dim3(T_STEPS), dim3(256), 0, stream>>>(x, xhi, xlo);
    lstm_seq<<<dim3(NWG), dim3(512), LDS_BYTES, stream>>>(
        Whh, Wih, bih, bhh, Wfc, xhi, xlo, h_hi, out, flags);
}